// Round 4
// baseline (2168.158 us; speedup 1.0000x reference)
//
#include <hip/hip_runtime.h>
#include <hip/hip_bf16.h>

#define SEQ   512
#define BATCH 128
#define EMBD  256
#define HIDD  512
#define NCLS  16
#define VOCAB 32000

typedef unsigned long long u64;
typedef __attribute__((ext_vector_type(8))) short  short8;
typedef __attribute__((ext_vector_type(4))) float  f32x4;

__device__ __forceinline__ float bfu(unsigned short u) {
    return __uint_as_float(((unsigned int)u) << 16);
}
__device__ __forceinline__ unsigned short f2bf(float f) {
    __hip_bfloat16 h = __float2bfloat16(f);
    return *reinterpret_cast<unsigned short*>(&h);
}
__device__ __forceinline__ float tanh_fast(float x) {
    float xc = fminf(fmaxf(x, -12.f), 12.f);
    float e  = __expf(2.f * xc);
    return 1.f - 2.f / (e + 1.f);
}
__device__ __forceinline__ void ep_store(float* p, float v)          { *p = v; }
__device__ __forceinline__ void ep_store(unsigned short* p, float v) { *p = f2bf(v); }
__device__ __forceinline__ void ld_ep4(const float* p, float* o) {
    float4 v = *reinterpret_cast<const float4*>(p);
    o[0] = v.x; o[1] = v.y; o[2] = v.z; o[3] = v.w;
}
__device__ __forceinline__ void ld_ep4(const unsigned short* p, float* o) {
    ushort4 v = *reinterpret_cast<const ushort4*>(p);
    o[0] = bfu(v.x); o[1] = bfu(v.y); o[2] = bfu(v.z); o[3] = bfu(v.w);
}

// ---------------------------------------------------------------------------
// W_hh and W_ih fp32 -> bf16 (row-major unchanged).
__global__ void cvt_weights(const float* __restrict__ W_hh,
                            const float* __restrict__ W_ih,
                            unsigned short* __restrict__ Whh_b,
                            unsigned short* __restrict__ Wih_b) {
    int i = blockIdx.x * 256 + threadIdx.x;
    if (i < HIDD * HIDD) {
        Whh_b[i] = f2bf(W_hh[i]);
    } else {
        int j = i - HIDD * HIDD;
        if (j < HIDD * EMBD) Wih_b[j] = f2bf(W_ih[j]);
    }
}

// ---------------------------------------------------------------------------
// EP[v][j] = emb[v]·W_ih[j] + b_ih[j] + b_hh[j].  grid 500 x 256 thr.
// Wave w: vocab mtile = bx*4+w (16 rows); emb read ONCE (held in regs as A),
// W_ih read from the pre-converted bf16 table (L2-resident, short8 loads).
template <typename EPT>
__global__ __launch_bounds__(256) void ep_gemm3(
    const float* __restrict__ emb, const unsigned short* __restrict__ Wih_b,
    const float* __restrict__ b_ih, const float* __restrict__ b_hh,
    EPT* __restrict__ EP) {
    const int w = threadIdx.x >> 6, l = threadIdx.x & 63;
    const int n = l & 15, lk = l >> 4;
    const int mtile = blockIdx.x * 4 + w;
    const int arow  = mtile * 16 + n;

    short8 areg[8];
    #pragma unroll
    for (int kk = 0; kk < 8; ++kk) {
        const int k0 = kk * 32 + lk * 8;
        const float4 a0 = *reinterpret_cast<const float4*>(emb + arow * EMBD + k0);
        const float4 a1 = *reinterpret_cast<const float4*>(emb + arow * EMBD + k0 + 4);
        short8 t;
        t[0]=(short)f2bf(a0.x); t[1]=(short)f2bf(a0.y); t[2]=(short)f2bf(a0.z); t[3]=(short)f2bf(a0.w);
        t[4]=(short)f2bf(a1.x); t[5]=(short)f2bf(a1.y); t[6]=(short)f2bf(a1.z); t[7]=(short)f2bf(a1.w);
        areg[kk] = t;
    }

    for (int nt = 0; nt < 32; ++nt) {
        const int col  = nt * 16 + n;
        const float bias = b_ih[col] + b_hh[col];
        f32x4 accA = {0.f,0.f,0.f,0.f}, accB = {0.f,0.f,0.f,0.f};
        #pragma unroll
        for (int kk = 0; kk < 8; ++kk) {
            const short8 bb = *reinterpret_cast<const short8*>(
                Wih_b + (size_t)col * EMBD + kk * 32 + lk * 8);
            if (kk & 1) accB = __builtin_amdgcn_mfma_f32_16x16x32_bf16(areg[kk], bb, accB, 0, 0, 0);
            else        accA = __builtin_amdgcn_mfma_f32_16x16x32_bf16(areg[kk], bb, accA, 0, 0, 0);
        }
        const f32x4 ac = accA + accB;
        #pragma unroll
        for (int r = 0; r < 4; ++r)
            ep_store(EP + (size_t)(mtile * 16 + lk * 4 + r) * HIDD + col, ac[r] + bias);
    }
}

// ---------------------------------------------------------------------------
// Single-CU weights-stationary RNN, role-swapped MFMA.
// grid = 8 (one WG per 16-batch group), 256 thr = 4 waves, 1 wave/SIMD.
// Wave w owns output cols [w*128, w*128+128): tiles 0..5 in 384 VGPRs,
// tiles 6,7 in a 128 KB LDS buffer (fragment order, conflict-free b128).
// h lives in LDS in B-fragment order (16 KB); writeback = one b64 per
// (lane, tile). Two barriers per step. No cross-WG communication.
template <typename EPT>
__global__ __launch_bounds__(256, 1) void rnn4(
    const int*            __restrict__ x,
    const unsigned short* __restrict__ Whh,   // bf16 [512][512]
    const EPT*            __restrict__ EP,    // [VOCAB][512]
    const float*          __restrict__ W_fc,
    const float*          __restrict__ b_fc,
    float*                __restrict__ out) {

    __shared__ short8 hfrag[16 * 64];       // 16 KB: slot = kk*64 + lane
    __shared__ short8 WT[4 * 2 * 16 * 64];  // 128 KB: ((w*2+t2)*16+kk)*64 + lane

    const int tid = threadIdx.x;
    const int w   = tid >> 6, l = tid & 63;
    const int n   = l & 15,  lk = l >> 4;
    const int b0  = blockIdx.x * 16;
    const int jw  = w * 128;

    // per-(lane, tile) h-publish byte offsets into hfrag:
    // element (batch n, k) lives at slot (k>>5)*64 + ((k>>3)&3)*16 + n, halfword k&7
    int sOff[8];
    #pragma unroll
    for (int tau = 0; tau < 8; ++tau) {
        const int j0 = jw + tau * 16 + lk * 4;
        const int blk = ((j0 >> 5) << 6) | n | (((j0 >> 3) & 3) << 4);
        sOff[tau] = blk * 16 + ((j0 & 4) ? 8 : 0);
    }
    char* const hc = reinterpret_cast<char*>(hfrag);

    // ---- t = 0: h1 = tanh(EP[tok0]) ----
    {
        const int tok = x[b0 + n];
        #pragma unroll
        for (int tau = 0; tau < 8; ++tau) {
            float e[4];
            ld_ep4(EP + (size_t)tok * HIDD + jw + tau * 16 + lk * 4, e);
            u64 q = (u64)f2bf(tanh_fast(e[0]))
                  | ((u64)f2bf(tanh_fast(e[1])) << 16)
                  | ((u64)f2bf(tanh_fast(e[2])) << 32)
                  | ((u64)f2bf(tanh_fast(e[3])) << 48);
            *reinterpret_cast<u64*>(hc + sOff[tau]) = q;
        }
    }

    // ---- stage LDS weight tiles (tiles 6,7 of each wave), fragment order ----
    for (int idx = tid; idx < 4 * 2 * 16 * 64; idx += 256) {
        const int w2 = idx >> 11;
        const int t2 = (idx >> 10) & 1;
        const int kk = (idx >> 6) & 15;
        const int l2 = idx & 63;
        WT[idx] = *reinterpret_cast<const short8*>(
            Whh + (size_t)(w2 * 128 + (6 + t2) * 16 + (l2 & 15)) * HIDD
                + kk * 32 + (l2 >> 4) * 8);
    }

    // ---- VGPR-resident weight fragments: tiles 0..5 ----
    short8 af[6][16];
    #pragma unroll
    for (int tau = 0; tau < 6; ++tau)
        #pragma unroll
        for (int kk = 0; kk < 16; ++kk)
            af[tau][kk] = *reinterpret_cast<const short8*>(
                Whh + (size_t)(jw + tau * 16 + n) * HIDD + kk * 32 + lk * 8);

    __syncthreads();

    const short8* const bp  = hfrag + l;
    const short8* const wt0 = WT + (w * 2 + 0) * 16 * 64 + l;
    const short8* const wt1 = WT + (w * 2 + 1) * 16 * 64 + l;

    for (int t = 1; t <= 511; ++t) {
        // EP gather for THIS step, issued before the MFMA loop (latency
        // hides under ~2300 cyc of LDS/MFMA), consumed after the barrier.
        float epc[8][4];
        {
            const int tok = x[t * BATCH + b0 + n];
            #pragma unroll
            for (int tau = 0; tau < 8; ++tau)
                ld_ep4(EP + (size_t)tok * HIDD + jw + tau * 16 + lk * 4, epc[tau]);
        }

        f32x4 acc[8] = {{0,0,0,0},{0,0,0,0},{0,0,0,0},{0,0,0,0},
                        {0,0,0,0},{0,0,0,0},{0,0,0,0},{0,0,0,0}};
        #pragma unroll
        for (int kk = 0; kk < 16; ++kk) {
            const short8 B = bp[kk * 64];   // shared h B-frag, conflict-free
            acc[0] = __builtin_amdgcn_mfma_f32_16x16x32_bf16(af[0][kk], B, acc[0], 0, 0, 0);
            acc[1] = __builtin_amdgcn_mfma_f32_16x16x32_bf16(af[1][kk], B, acc[1], 0, 0, 0);
            acc[2] = __builtin_amdgcn_mfma_f32_16x16x32_bf16(af[2][kk], B, acc[2], 0, 0, 0);
            acc[3] = __builtin_amdgcn_mfma_f32_16x16x32_bf16(af[3][kk], B, acc[3], 0, 0, 0);
            acc[4] = __builtin_amdgcn_mfma_f32_16x16x32_bf16(af[4][kk], B, acc[4], 0, 0, 0);
            acc[5] = __builtin_amdgcn_mfma_f32_16x16x32_bf16(af[5][kk], B, acc[5], 0, 0, 0);
            const short8 w6 = wt0[kk * 64];
            acc[6] = __builtin_amdgcn_mfma_f32_16x16x32_bf16(w6, B, acc[6], 0, 0, 0);
            const short8 w7 = wt1[kk * 64];
            acc[7] = __builtin_amdgcn_mfma_f32_16x16x32_bf16(w7, B, acc[7], 0, 0, 0);
        }
        __syncthreads();   // all waves' hfrag reads complete

        #pragma unroll
        for (int tau = 0; tau < 8; ++tau) {
            u64 q = (u64)f2bf(tanh_fast(acc[tau][0] + epc[tau][0]))
                  | ((u64)f2bf(tanh_fast(acc[tau][1] + epc[tau][1])) << 16)
                  | ((u64)f2bf(tanh_fast(acc[tau][2] + epc[tau][2])) << 32)
                  | ((u64)f2bf(tanh_fast(acc[tau][3] + epc[tau][3])) << 48);
            *reinterpret_cast<u64*>(hc + sOff[tau]) = q;   // b64, ~conflict-free
        }
        __syncthreads();   // h_{t+1} visible
    }

    // ---- FC epilogue: out[b0+n2][c] = h512[n2]·W_fc[c] + b_fc[c] ----
    {
        const int n2 = tid >> 4, c = tid & 15;
        float sum = b_fc[c];
        const unsigned short* hp = reinterpret_cast<const unsigned short*>(hfrag);
        for (int kk = 0; kk < 16; ++kk)
            #pragma unroll
            for (int lo = 0; lo < 4; ++lo) {
                const int bb = (kk << 6) | n2 | (lo << 4);
                #pragma unroll
                for (int i = 0; i < 8; ++i)
                    sum += bfu(hp[bb * 8 + i]) * W_fc[c * HIDD + kk * 32 + lo * 8 + i];
            }
        out[(b0 + n2) * NCLS + c] = sum;
    }
}

// ---------------------------------------------------------------------------
// Tier-C fallback (round-1, known good) for small ws.
__global__ void cvt_kernel(const float* __restrict__ W_ih,
                           const float* __restrict__ W_hh,
                           const float* __restrict__ b_ih,
                           const float* __restrict__ b_hh,
                           unsigned short* __restrict__ Wpk,
                           unsigned short* __restrict__ Wipk,
                           float* __restrict__ bias) {
    const int NW = HIDD * HIDD;
    const int NI = HIDD * EMBD;
    int gid = blockIdx.x * blockDim.x + threadIdx.x;
    if (gid < NW) {
        int j = gid >> 9, k = gid & (HIDD - 1);
        Wpk[((k >> 2) * HIDD + j) * 4 + (k & 3)] = f2bf(W_hh[gid]);
    } else if (gid < NW + NI) {
        int g2 = gid - NW, j = g2 >> 8, e = g2 & (EMBD - 1);
        Wipk[((e >> 2) * HIDD + j) * 4 + (e & 3)] = f2bf(W_ih[g2]);
    } else if (gid < NW + NI + HIDD) {
        int j = gid - NW - NI;
        bias[j] = b_ih[j] + b_hh[j];
    }
}

__global__ __launch_bounds__(512) void rnn_kernel(
    const int* __restrict__ x, const float* __restrict__ emb,
    const unsigned short* __restrict__ Wpk, const unsigned short* __restrict__ Wipk,
    const float* __restrict__ bias, const float* __restrict__ W_fc,
    const float* __restrict__ b_fc, float* __restrict__ out) {
    __shared__ __align__(16) float hL[HIDD];
    __shared__ __align__(16) float xe[EMBD];
    __shared__ float red[512];
    const int tid = threadIdx.x, b = blockIdx.x, j = tid;
    hL[j] = 0.0f;
    const float bj = bias[j];
    const ushort4* Wp4 = reinterpret_cast<const ushort4*>(Wpk);
    const ushort4* Wi4 = reinterpret_cast<const ushort4*>(Wipk);
    for (int t = 0; t < SEQ; ++t) {
        const int tok = x[t * BATCH + b];
        if (tid < EMBD) xe[tid] = emb[tok * EMBD + tid];
        __syncthreads();
        float a0 = bj, a1 = 0.0f;
        #pragma unroll 8
        for (int e4 = 0; e4 < EMBD / 4; ++e4) {
            const float4 xv = *reinterpret_cast<const float4*>(&xe[e4 * 4]);
            const ushort4 ww = Wi4[e4 * HIDD + j];
            a0 += xv.x * bfu(ww.x) + xv.y * bfu(ww.y);
            a1 += xv.z * bfu(ww.z) + xv.w * bfu(ww.w);
        }
        #pragma unroll 8
        for (int k4 = 0; k4 < HIDD / 4; ++k4) {
            const float4 hvv = *reinterpret_cast<const float4*>(&hL[k4 * 4]);
            const ushort4 ww = Wp4[k4 * HIDD + j];
            a0 += hvv.x * bfu(ww.x) + hvv.y * bfu(ww.y);
            a1 += hvv.z * bfu(ww.z) + hvv.w * bfu(ww.w);
        }
        __syncthreads();
        hL[j] = tanhf(a0 + a1);
    }
    __syncthreads();
    {
        const int c = tid >> 5, ks = tid & 31;
        float p = 0.0f;
        #pragma unroll
        for (int jj = 0; jj < HIDD / 32; ++jj) {
            const int jd = ks * (HIDD / 32) + jj;
            p += hL[jd] * W_fc[c * HIDD + jd];
        }
        red[tid] = p;
        __syncthreads();
        if (tid < NCLS) {
            float ss = b_fc[tid];
            #pragma unroll
            for (int i = 0; i < 32; ++i) ss += red[tid * 32 + i];
            out[b * NCLS + tid] = ss;
        }
    }
}

// ---------------------------------------------------------------------------
extern "C" void kernel_launch(void* const* d_in, const int* in_sizes, int n_in,
                              void* d_out, int out_size, void* d_ws, size_t ws_size,
                              hipStream_t stream) {
    const int*   x    = (const int*)  d_in[0];
    const float* emb  = (const float*)d_in[1];
    const float* W_ih = (const float*)d_in[2];
    const float* W_hh = (const float*)d_in[3];
    const float* b_ih = (const float*)d_in[4];
    const float* b_hh = (const float*)d_in[5];
    const float* W_fc = (const float*)d_in[6];
    const float* b_fc = (const float*)d_in[7];
    float* out = (float*)d_out;

    const size_t WHH_B = (size_t)HIDD * HIDD * 2;   // 512 KB
    const size_t WIH_B = (size_t)HIDD * EMBD * 2;   // 256 KB
    const size_t EPN   = (size_t)VOCAB * HIDD;
    const int    CVT_G = (HIDD * HIDD + HIDD * EMBD + 255) / 256;

    if (ws_size >= WHH_B + WIH_B + EPN * 4) {
        unsigned short* Whh_b = (unsigned short*)d_ws;
        unsigned short* Wih_b = (unsigned short*)((char*)d_ws + WHH_B);
        float*          EP    = (float*)((char*)d_ws + WHH_B + WIH_B);
        cvt_weights<<<CVT_G, 256, 0, stream>>>(W_hh, W_ih, Whh_b, Wih_b);
        ep_gemm3<float><<<VOCAB / 64, 256, 0, stream>>>(emb, Wih_b, b_ih, b_hh, EP);
        rnn4<float><<<8, 256, 0, stream>>>(x, Whh_b, EP, W_fc, b_fc, out);
    } else if (ws_size >= WHH_B + WIH_B + EPN * 2) {
        unsigned short* Whh_b = (unsigned short*)d_ws;
        unsigned short* Wih_b = (unsigned short*)((char*)d_ws + WHH_B);
        unsigned short* EP    = (unsigned short*)((char*)d_ws + WHH_B + WIH_B);
        cvt_weights<<<CVT_G, 256, 0, stream>>>(W_hh, W_ih, Whh_b, Wih_b);
        ep_gemm3<unsigned short><<<VOCAB / 64, 256, 0, stream>>>(emb, Wih_b, b_ih, b_hh, EP);
        rnn4<unsigned short><<<8, 256, 0, stream>>>(x, Whh_b, EP, W_fc, b_fc, out);
    } else {
        unsigned short* Wpk  = (unsigned short*)d_ws;
        unsigned short* Wipk = Wpk + HIDD * HIDD;
        float*          bias = (float*)(Wipk + HIDD * EMBD);
        const int total = HIDD * HIDD + HIDD * EMBD + HIDD;
        cvt_kernel<<<(total + 255) / 256, 256, 0, stream>>>(W_ih, W_hh, b_ih, b_hh, Wpk, Wipk, bias);
        rnn_kernel<<<BATCH, 512, 0, stream>>>(x, emb, Wpk, Wipk, bias, W_fc, b_fc, out);
    }
}

// Round 5
// 2073.323 us; speedup vs baseline: 1.0457x; 1.0457x over previous
//
#include <hip/hip_runtime.h>
#include <hip/hip_bf16.h>

#define SEQ   512
#define BATCH 128
#define EMBD  256
#define HIDD  512
#define NCLS  16
#define VOCAB 32000

typedef unsigned long long u64;
typedef __attribute__((ext_vector_type(8))) short  short8;
typedef __attribute__((ext_vector_type(4))) float  f32x4;

__device__ __forceinline__ float bfu(unsigned short u) {
    return __uint_as_float(((unsigned int)u) << 16);
}
__device__ __forceinline__ unsigned short f2bf(float f) {
    __hip_bfloat16 h = __float2bfloat16(f);
    return *reinterpret_cast<unsigned short*>(&h);
}
__device__ __forceinline__ float tanh_fast(float x) {
    float xc = fminf(fmaxf(x, -12.f), 12.f);
    float e  = __expf(2.f * xc);
    return 1.f - 2.f / (e + 1.f);
}
__device__ __forceinline__ void ep_store(float* p, float v)          { *p = v; }
__device__ __forceinline__ void ep_store(unsigned short* p, float v) { *p = f2bf(v); }
__device__ __forceinline__ void ld_ep4(const float* p, float* o) {
    float4 v = *reinterpret_cast<const float4*>(p);
    o[0] = v.x; o[1] = v.y; o[2] = v.z; o[3] = v.w;
}
__device__ __forceinline__ void ld_ep4(const unsigned short* p, float* o) {
    ushort4 v = *reinterpret_cast<const ushort4*>(p);
    o[0] = bfu(v.x); o[1] = bfu(v.y); o[2] = bfu(v.z); o[3] = bfu(v.w);
}

// ---------------------------------------------------------------------------
// W_hh and W_ih fp32 -> bf16 (row-major unchanged).
__global__ void cvt_weights(const float* __restrict__ W_hh,
                            const float* __restrict__ W_ih,
                            unsigned short* __restrict__ Whh_b,
                            unsigned short* __restrict__ Wih_b) {
    int i = blockIdx.x * 256 + threadIdx.x;
    if (i < HIDD * HIDD) {
        Whh_b[i] = f2bf(W_hh[i]);
    } else {
        int j = i - HIDD * HIDD;
        if (j < HIDD * EMBD) Wih_b[j] = f2bf(W_ih[j]);
    }
}

// ---------------------------------------------------------------------------
// EP[v][j] = emb[v]·W_ih[j] + b_ih[j] + b_hh[j].  grid 500 x 256 thr.
// emb read once (regs as A); W_ih from pre-converted bf16 table.
template <typename EPT>
__global__ __launch_bounds__(256) void ep_gemm3(
    const float* __restrict__ emb, const unsigned short* __restrict__ Wih_b,
    const float* __restrict__ b_ih, const float* __restrict__ b_hh,
    EPT* __restrict__ EP) {
    const int w = threadIdx.x >> 6, l = threadIdx.x & 63;
    const int n = l & 15, lk = l >> 4;
    const int mtile = blockIdx.x * 4 + w;
    const int arow  = mtile * 16 + n;

    short8 areg[8];
    #pragma unroll
    for (int kk = 0; kk < 8; ++kk) {
        const int k0 = kk * 32 + lk * 8;
        const float4 a0 = *reinterpret_cast<const float4*>(emb + arow * EMBD + k0);
        const float4 a1 = *reinterpret_cast<const float4*>(emb + arow * EMBD + k0 + 4);
        short8 t;
        t[0]=(short)f2bf(a0.x); t[1]=(short)f2bf(a0.y); t[2]=(short)f2bf(a0.z); t[3]=(short)f2bf(a0.w);
        t[4]=(short)f2bf(a1.x); t[5]=(short)f2bf(a1.y); t[6]=(short)f2bf(a1.z); t[7]=(short)f2bf(a1.w);
        areg[kk] = t;
    }

    for (int nt = 0; nt < 32; ++nt) {
        const int col  = nt * 16 + n;
        const float bias = b_ih[col] + b_hh[col];
        f32x4 accA = {0.f,0.f,0.f,0.f}, accB = {0.f,0.f,0.f,0.f};
        #pragma unroll
        for (int kk = 0; kk < 8; ++kk) {
            const short8 bb = *reinterpret_cast<const short8*>(
                Wih_b + (size_t)col * EMBD + kk * 32 + lk * 8);
            if (kk & 1) accB = __builtin_amdgcn_mfma_f32_16x16x32_bf16(areg[kk], bb, accB, 0, 0, 0);
            else        accA = __builtin_amdgcn_mfma_f32_16x16x32_bf16(areg[kk], bb, accA, 0, 0, 0);
        }
        const f32x4 ac = accA + accB;
        #pragma unroll
        for (int r = 0; r < 4; ++r)
            ep_store(EP + (size_t)(mtile * 16 + lk * 4 + r) * HIDD + col, ac[r] + bias);
    }
}

// ---------------------------------------------------------------------------
// Single-CU weights-stationary RNN, role-swapped MFMA, 8 waves (2/SIMD).
// grid = 8 (one WG per 16-batch group), 512 thr.
// Wave w owns output cols [w*64, w*64+64): tiles 0..2 in 192 VGPRs (storage
// rotated by per-wave kk stagger so all indices are compile-time), tile 3 in
// a 128 KB LDS buffer (fragment order, conflict-free linear b128).
// h in LDS in B-fragment order (16 KB); writeback = one b64 per (lane,tile).
template <typename EPT>
__global__ __launch_bounds__(512, 2) void rnn5(
    const int*            __restrict__ x,
    const unsigned short* __restrict__ Whh,   // bf16 [512][512]
    const EPT*            __restrict__ EP,    // [VOCAB][512]
    const float*          __restrict__ W_fc,
    const float*          __restrict__ b_fc,
    float*                __restrict__ out) {

    __shared__ short8 hfrag[16 * 64];      // 16 KB: slot = kk*64 + lane
    __shared__ short8 WT[8 * 16 * 64];     // 128 KB: (w*16+kk)*64 + lane

    const int tid = threadIdx.x;
    const int w   = tid >> 6, l = tid & 63;
    const int n   = l & 15,  lk = l >> 4;
    const int b0  = blockIdx.x * 16;
    const int jw  = w * 64;
    const int rot = (w * 2) & 15;          // per-wave kk stagger

    // per-(lane, tile) h-publish byte offsets into fragment-order hfrag:
    // element (batch n, k) at slot (k>>5)*64 + ((k>>3)&3)*16 + n, halfword k&7
    int sOff[4];
    #pragma unroll
    for (int tau = 0; tau < 4; ++tau) {
        const int j0 = jw + tau * 16 + lk * 4;
        const int blk = ((j0 >> 5) << 6) | n | (((j0 >> 3) & 3) << 4);
        sOff[tau] = blk * 16 + ((j0 & 4) ? 8 : 0);
    }
    char* const hc = reinterpret_cast<char*>(hfrag);

    // ---- t = 0: h1 = tanh(EP[tok0]) ----
    {
        const int tok = x[b0 + n];
        #pragma unroll
        for (int tau = 0; tau < 4; ++tau) {
            float e[4];
            ld_ep4(EP + (size_t)tok * HIDD + jw + tau * 16 + lk * 4, e);
            u64 q = (u64)f2bf(tanh_fast(e[0]))
                  | ((u64)f2bf(tanh_fast(e[1])) << 16)
                  | ((u64)f2bf(tanh_fast(e[2])) << 32)
                  | ((u64)f2bf(tanh_fast(e[3])) << 48);
            *reinterpret_cast<u64*>(hc + sOff[tau]) = q;
        }
    }

    // ---- stage LDS weight tile (tile 3 of each wave), fragment order ----
    for (int idx = tid; idx < 8 * 16 * 64; idx += 512) {
        const int w2 = idx >> 10;          // 0..7
        const int kk = (idx >> 6) & 15;
        const int l2 = idx & 63;
        WT[idx] = *reinterpret_cast<const short8*>(
            Whh + (size_t)(w2 * 64 + 48 + (l2 & 15)) * HIDD + kk * 32 + (l2 >> 4) * 8);
    }

    // ---- VGPR-resident weight fragments, tiles 0..2, rotated storage:
    // af[tau][kx] holds the fragment for kk = (kx + rot) & 15.
    short8 af[3][16];
    #pragma unroll
    for (int tau = 0; tau < 3; ++tau)
        #pragma unroll
        for (int kx = 0; kx < 16; ++kx) {
            const int kkr = (kx + rot) & 15;
            af[tau][kx] = *reinterpret_cast<const short8*>(
                Whh + (size_t)(jw + tau * 16 + n) * HIDD + kkr * 32 + lk * 8);
        }

    __syncthreads();

    const short8* const bp  = hfrag + l;
    const short8* const wtp = WT + w * 16 * 64 + l;

    for (int t = 1; t <= 511; ++t) {
        // EP gather for THIS step, issued early, consumed after the barrier.
        float epc[4][4];
        {
            const int tok = x[t * BATCH + b0 + n];
            #pragma unroll
            for (int tau = 0; tau < 4; ++tau)
                ld_ep4(EP + (size_t)tok * HIDD + jw + tau * 16 + lk * 4, epc[tau]);
        }

        f32x4 acc[4] = {{0,0,0,0},{0,0,0,0},{0,0,0,0},{0,0,0,0}};
        #pragma unroll
        for (int kx = 0; kx < 16; ++kx) {
            const int kkr = (kx + rot) & 15;        // runtime LDS addr, static af idx
            const short8 B = bp[kkr * 64];          // h B-frag, linear conflict-free
            acc[0] = __builtin_amdgcn_mfma_f32_16x16x32_bf16(af[0][kx], B, acc[0], 0, 0, 0);
            acc[1] = __builtin_amdgcn_mfma_f32_16x16x32_bf16(af[1][kx], B, acc[1], 0, 0, 0);
            acc[2] = __builtin_amdgcn_mfma_f32_16x16x32_bf16(af[2][kx], B, acc[2], 0, 0, 0);
            const short8 w3 = wtp[kkr * 64];        // weight tile 3, linear
            acc[3] = __builtin_amdgcn_mfma_f32_16x16x32_bf16(w3, B, acc[3], 0, 0, 0);
        }
        __syncthreads();   // all waves' hfrag reads complete

        #pragma unroll
        for (int tau = 0; tau < 4; ++tau) {
            u64 q = (u64)f2bf(tanh_fast(acc[tau][0] + epc[tau][0]))
                  | ((u64)f2bf(tanh_fast(acc[tau][1] + epc[tau][1])) << 16)
                  | ((u64)f2bf(tanh_fast(acc[tau][2] + epc[tau][2])) << 32)
                  | ((u64)f2bf(tanh_fast(acc[tau][3] + epc[tau][3])) << 48);
            *reinterpret_cast<u64*>(hc + sOff[tau]) = q;   // aligned b64
        }
        __syncthreads();   // h_{t+1} visible
    }

    // ---- FC epilogue: out[b0+n2][c] = h512[n2]·W_fc[c] + b_fc[c] ----
    if (tid < 256) {
        const int n2 = tid >> 4, c = tid & 15;
        float sum = b_fc[c];
        const unsigned short* hp = reinterpret_cast<const unsigned short*>(hfrag);
        for (int kk = 0; kk < 16; ++kk)
            #pragma unroll
            for (int lo = 0; lo < 4; ++lo) {
                const int bb = (kk << 6) | n2 | (lo << 4);
                #pragma unroll
                for (int i = 0; i < 8; ++i)
                    sum += bfu(hp[bb * 8 + i]) * W_fc[c * HIDD + kk * 32 + lo * 8 + i];
            }
        out[(b0 + n2) * NCLS + c] = sum;
    }
}

// ---------------------------------------------------------------------------
// Tier-C fallback (round-1, known good) for small ws.
__global__ void cvt_kernel(const float* __restrict__ W_ih,
                           const float* __restrict__ W_hh,
                           const float* __restrict__ b_ih,
                           const float* __restrict__ b_hh,
                           unsigned short* __restrict__ Wpk,
                           unsigned short* __restrict__ Wipk,
                           float* __restrict__ bias) {
    const int NW = HIDD * HIDD;
    const int NI = HIDD * EMBD;
    int gid = blockIdx.x * blockDim.x + threadIdx.x;
    if (gid < NW) {
        int j = gid >> 9, k = gid & (HIDD - 1);
        Wpk[((k >> 2) * HIDD + j) * 4 + (k & 3)] = f2bf(W_hh[gid]);
    } else if (gid < NW + NI) {
        int g2 = gid - NW, j = g2 >> 8, e = g2 & (EMBD - 1);
        Wipk[((e >> 2) * HIDD + j) * 4 + (e & 3)] = f2bf(W_ih[g2]);
    } else if (gid < NW + NI + HIDD) {
        int j = gid - NW - NI;
        bias[j] = b_ih[j] + b_hh[j];
    }
}

__global__ __launch_bounds__(512) void rnn_kernel(
    const int* __restrict__ x, const float* __restrict__ emb,
    const unsigned short* __restrict__ Wpk, const unsigned short* __restrict__ Wipk,
    const float* __restrict__ bias, const float* __restrict__ W_fc,
    const float* __restrict__ b_fc, float* __restrict__ out) {
    __shared__ __align__(16) float hL[HIDD];
    __shared__ __align__(16) float xe[EMBD];
    __shared__ float red[512];
    const int tid = threadIdx.x, b = blockIdx.x, j = tid;
    hL[j] = 0.0f;
    const float bj = bias[j];
    const ushort4* Wp4 = reinterpret_cast<const ushort4*>(Wpk);
    const ushort4* Wi4 = reinterpret_cast<const ushort4*>(Wipk);
    for (int t = 0; t < SEQ; ++t) {
        const int tok = x[t * BATCH + b];
        if (tid < EMBD) xe[tid] = emb[tok * EMBD + tid];
        __syncthreads();
        float a0 = bj, a1 = 0.0f;
        #pragma unroll 8
        for (int e4 = 0; e4 < EMBD / 4; ++e4) {
            const float4 xv = *reinterpret_cast<const float4*>(&xe[e4 * 4]);
            const ushort4 ww = Wi4[e4 * HIDD + j];
            a0 += xv.x * bfu(ww.x) + xv.y * bfu(ww.y);
            a1 += xv.z * bfu(ww.z) + xv.w * bfu(ww.w);
        }
        #pragma unroll 8
        for (int k4 = 0; k4 < HIDD / 4; ++k4) {
            const float4 hvv = *reinterpret_cast<const float4*>(&hL[k4 * 4]);
            const ushort4 ww = Wp4[k4 * HIDD + j];
            a0 += hvv.x * bfu(ww.x) + hvv.y * bfu(ww.y);
            a1 += hvv.z * bfu(ww.z) + hvv.w * bfu(ww.w);
        }
        __syncthreads();
        hL[j] = tanhf(a0 + a1);
    }
    __syncthreads();
    {
        const int c = tid >> 5, ks = tid & 31;
        float p = 0.0f;
        #pragma unroll
        for (int jj = 0; jj < HIDD / 32; ++jj) {
            const int jd = ks * (HIDD / 32) + jj;
            p += hL[jd] * W_fc[c * HIDD + jd];
        }
        red[tid] = p;
        __syncthreads();
        if (tid < NCLS) {
            float ss = b_fc[tid];
            #pragma unroll
            for (int i = 0; i < 32; ++i) ss += red[tid * 32 + i];
            out[b * NCLS + tid] = ss;
        }
    }
}

// ---------------------------------------------------------------------------
extern "C" void kernel_launch(void* const* d_in, const int* in_sizes, int n_in,
                              void* d_out, int out_size, void* d_ws, size_t ws_size,
                              hipStream_t stream) {
    const int*   x    = (const int*)  d_in[0];
    const float* emb  = (const float*)d_in[1];
    const float* W_ih = (const float*)d_in[2];
    const float* W_hh = (const float*)d_in[3];
    const float* b_ih = (const float*)d_in[4];
    const float* b_hh = (const float*)d_in[5];
    const float* W_fc = (const float*)d_in[6];
    const float* b_fc = (const float*)d_in[7];
    float* out = (float*)d_out;

    const size_t WHH_B = (size_t)HIDD * HIDD * 2;   // 512 KB
    const size_t WIH_B = (size_t)HIDD * EMBD * 2;   // 256 KB
    const size_t EPN   = (size_t)VOCAB * HIDD;
    const int    CVT_G = (HIDD * HIDD + HIDD * EMBD + 255) / 256;

    if (ws_size >= WHH_B + WIH_B + EPN * 4) {
        unsigned short* Whh_b = (unsigned short*)d_ws;
        unsigned short* Wih_b = (unsigned short*)((char*)d_ws + WHH_B);
        float*          EP    = (float*)((char*)d_ws + WHH_B + WIH_B);
        cvt_weights<<<CVT_G, 256, 0, stream>>>(W_hh, W_ih, Whh_b, Wih_b);
        ep_gemm3<float><<<VOCAB / 64, 256, 0, stream>>>(emb, Wih_b, b_ih, b_hh, EP);
        rnn5<float><<<8, 512, 0, stream>>>(x, Whh_b, EP, W_fc, b_fc, out);
    } else if (ws_size >= WHH_B + WIH_B + EPN * 2) {
        unsigned short* Whh_b = (unsigned short*)d_ws;
        unsigned short* Wih_b = (unsigned short*)((char*)d_ws + WHH_B);
        unsigned short* EP    = (unsigned short*)((char*)d_ws + WHH_B + WIH_B);
        cvt_weights<<<CVT_G, 256, 0, stream>>>(W_hh, W_ih, Whh_b, Wih_b);
        ep_gemm3<unsigned short><<<VOCAB / 64, 256, 0, stream>>>(emb, Wih_b, b_ih, b_hh, EP);
        rnn5<unsigned short><<<8, 512, 0, stream>>>(x, Whh_b, EP, W_fc, b_fc, out);
    } else {
        unsigned short* Wpk  = (unsigned short*)d_ws;
        unsigned short* Wipk = Wpk + HIDD * HIDD;
        float*          bias = (float*)(Wipk + HIDD * EMBD);
        const int total = HIDD * HIDD + HIDD * EMBD + HIDD;
        cvt_kernel<<<(total + 255) / 256, 256, 0, stream>>>(W_ih, W_hh, b_ih, b_hh, Wpk, Wipk, bias);
        rnn_kernel<<<BATCH, 512, 0, stream>>>(x, emb, Wpk, Wipk, bias, W_fc, b_fc, out);
    }
}

// Round 6
// 1264.282 us; speedup vs baseline: 1.7149x; 1.6399x over previous
//
#include <hip/hip_runtime.h>
#include <hip/hip_bf16.h>

#define SEQ   512
#define BATCH 128
#define EMBD  256
#define HIDD  512
#define NCLS  16
#define VOCAB 32000

typedef unsigned long long u64;
typedef __attribute__((ext_vector_type(8))) short  short8;
typedef __attribute__((ext_vector_type(4))) float  f32x4;
typedef __attribute__((ext_vector_type(4))) int    i32x4;

__device__ __forceinline__ float bfu(unsigned short u) {
    return __uint_as_float(((unsigned int)u) << 16);
}
__device__ __forceinline__ unsigned short f2bf(float f) {
    __hip_bfloat16 h = __float2bfloat16(f);
    return *reinterpret_cast<unsigned short*>(&h);
}
__device__ __forceinline__ float tanh_fast(float x) {
    float xc = fminf(fmaxf(x, -12.f), 12.f);
    float e  = __expf(2.f * xc);
    return 1.f - 2.f / (e + 1.f);
}
__device__ __forceinline__ void ep_store(float* p, float v)          { *p = v; }
__device__ __forceinline__ void ep_store(unsigned short* p, float v) { *p = f2bf(v); }
__device__ __forceinline__ void ld_ep4(const float* p, float* o) {
    float4 v = *reinterpret_cast<const float4*>(p);
    o[0] = v.x; o[1] = v.y; o[2] = v.z; o[3] = v.w;
}
__device__ __forceinline__ void ld_ep4(const unsigned short* p, float* o) {
    ushort4 v = *reinterpret_cast<const ushort4*>(p);
    o[0] = bfu(v.x); o[1] = bfu(v.y); o[2] = bfu(v.z); o[3] = bfu(v.w);
}

// ---------------------------------------------------------------------------
// absmax(W_hh) -> scl[0]; combined dequant factor sW*sh -> scl[1].
__global__ __launch_bounds__(1024) void absmax_whh(const float* __restrict__ W,
                                                   float* __restrict__ scl) {
    __shared__ float red[1024];
    float m = 0.f;
    for (int i = threadIdx.x; i < (HIDD * HIDD) / 4; i += 1024) {
        const float4 v = reinterpret_cast<const float4*>(W)[i];
        m = fmaxf(m, fmaxf(fmaxf(fabsf(v.x), fabsf(v.y)),
                           fmaxf(fabsf(v.z), fabsf(v.w))));
    }
    red[threadIdx.x] = m;
    __syncthreads();
    for (int s = 512; s > 0; s >>= 1) {
        if (threadIdx.x < s) red[threadIdx.x] = fmaxf(red[threadIdx.x], red[threadIdx.x + s]);
        __syncthreads();
    }
    if (threadIdx.x == 0) {
        scl[0] = red[0];
        scl[1] = red[0] / 16129.f;   // (absmax/127) * (1/127)
    }
}

// W_hh fp32 -> int8 row-major (scale = absmax/127).
__global__ void quant_whh(const float* __restrict__ W, const float* __restrict__ scl,
                          signed char* __restrict__ Wq) {
    const int i = blockIdx.x * 256 + threadIdx.x;
    const float inv = 127.f / scl[0];
    Wq[i] = (signed char)(int)rintf(W[i] * inv);
}

// W_ih fp32 -> bf16 row-major.
__global__ void cvt_wih(const float* __restrict__ W, unsigned short* __restrict__ Wb) {
    const int i = blockIdx.x * 256 + threadIdx.x;
    Wb[i] = f2bf(W[i]);
}

// ---------------------------------------------------------------------------
// EP[v][j] = emb[v]·W_ih[j] + b_ih[j] + b_hh[j].  grid 500 x 256 thr.
template <typename EPT>
__global__ __launch_bounds__(256) void ep_gemm3(
    const float* __restrict__ emb, const unsigned short* __restrict__ Wih_b,
    const float* __restrict__ b_ih, const float* __restrict__ b_hh,
    EPT* __restrict__ EP) {
    const int w = threadIdx.x >> 6, l = threadIdx.x & 63;
    const int n = l & 15, lk = l >> 4;
    const int mtile = blockIdx.x * 4 + w;
    const int arow  = mtile * 16 + n;

    short8 areg[8];
    #pragma unroll
    for (int kk = 0; kk < 8; ++kk) {
        const int k0 = kk * 32 + lk * 8;
        const float4 a0 = *reinterpret_cast<const float4*>(emb + arow * EMBD + k0);
        const float4 a1 = *reinterpret_cast<const float4*>(emb + arow * EMBD + k0 + 4);
        short8 t;
        t[0]=(short)f2bf(a0.x); t[1]=(short)f2bf(a0.y); t[2]=(short)f2bf(a0.z); t[3]=(short)f2bf(a0.w);
        t[4]=(short)f2bf(a1.x); t[5]=(short)f2bf(a1.y); t[6]=(short)f2bf(a1.z); t[7]=(short)f2bf(a1.w);
        areg[kk] = t;
    }

    for (int nt = 0; nt < 32; ++nt) {
        const int col  = nt * 16 + n;
        const float bias = b_ih[col] + b_hh[col];
        f32x4 accA = {0.f,0.f,0.f,0.f}, accB = {0.f,0.f,0.f,0.f};
        #pragma unroll
        for (int kk = 0; kk < 8; ++kk) {
            const short8 bb = *reinterpret_cast<const short8*>(
                Wih_b + (size_t)col * EMBD + kk * 32 + lk * 8);
            if (kk & 1) accB = __builtin_amdgcn_mfma_f32_16x16x32_bf16(areg[kk], bb, accB, 0, 0, 0);
            else        accA = __builtin_amdgcn_mfma_f32_16x16x32_bf16(areg[kk], bb, accA, 0, 0, 0);
        }
        const f32x4 ac = accA + accB;
        #pragma unroll
        for (int r = 0; r < 4; ++r)
            ep_store(EP + (size_t)(mtile * 16 + lk * 4 + r) * HIDD + col, ac[r] + bias);
    }
}

// ---------------------------------------------------------------------------
// int8 weights-stationary RNN. grid = 8 (one WG / 16-batch group), 512 thr
// (8 waves, 2/SIMD). Wave w owns cols [w*64, w*64+64): ALL its weights live
// in 128 regs/thread as mfma_i32_16x16x64_i8 A-frags. h int8 double-buffered
// in LDS (2 x 16 x 512 B) with 16B-granule XOR swizzle (g^n): reads/writes
// are <=2-way (free). One barrier per step.
//  A-frag: lane l -> row j = jt*16+(l&15), k = (l>>4)*16 + 0..15
//  B-frag: lane l -> row n = l&15,          k = (l>>4)*16 + 0..15
//  C/D   : col n = l&15, row j = jt*16 + (l>>4)*4 + r  -> 4 consecutive j
template <typename EPT>
__global__ __launch_bounds__(512, 2) void rnn6(
    const int*         __restrict__ x,
    const signed char* __restrict__ Wq,    // int8 [512][512]
    const float*       __restrict__ scl,   // [1] = sW*sh
    const EPT*         __restrict__ EP,    // [VOCAB][512]
    const float*       __restrict__ W_fc,
    const float*       __restrict__ b_fc,
    float*             __restrict__ out) {

    __shared__ __align__(16) char hq[2 * 16 * 512];   // 16 KB total

    const int tid = threadIdx.x;
    const int w   = tid >> 6, l = tid & 63;
    const int n   = l & 15,  lk = l >> 4;
    const int b0  = blockIdx.x * 16;
    const int jw  = w * 64;
    const float fs = scl[1];

    // loop-invariant LDS byte offsets (into buffer 0)
    int rdA[8];
    #pragma unroll
    for (int kf = 0; kf < 8; ++kf) {
        const int g = kf * 4 + lk;
        rdA[kf] = n * 512 + ((g ^ n) << 4);
    }
    int wrA[4];
    #pragma unroll
    for (int tau = 0; tau < 4; ++tau) {
        const int j0 = jw + tau * 16 + lk * 4;
        wrA[tau] = n * 512 + (((j0 >> 4) ^ n) << 4) + (j0 & 15);
    }

    // ---- register-resident int8 A-frags: wave's 64 weight rows ----
    i32x4 af[4][8];
    #pragma unroll
    for (int tau = 0; tau < 4; ++tau)
        #pragma unroll
        for (int kf = 0; kf < 8; ++kf)
            af[tau][kf] = *reinterpret_cast<const i32x4*>(
                Wq + (size_t)(jw + tau * 16 + n) * HIDD + kf * 64 + lk * 16);

    // ---- t = 0: h1 = tanh(EP[tok0]) -> buffer 1 ----
    {
        const int tok0 = x[b0 + n];
        #pragma unroll
        for (int tau = 0; tau < 4; ++tau) {
            float e[4];
            ld_ep4(EP + (size_t)tok0 * HIDD + jw + tau * 16 + lk * 4, e);
            unsigned pk = 0;
            #pragma unroll
            for (int r = 0; r < 4; ++r) {
                const int q = (int)rintf(tanh_fast(e[r]) * 127.f);
                pk |= ((unsigned)(q & 255)) << (8 * r);
            }
            *reinterpret_cast<unsigned*>(hq + 8192 + wrA[tau]) = pk;
        }
    }
    int tokc = x[BATCH + b0 + n];   // token for t=1
    __syncthreads();

    #pragma unroll 2
    for (int t = 1; t <= 511; ++t) {
        const int ro = (t & 1) << 13;          // read buf[t&1]
        const int wo = 8192 - ro;              // write buf[(t+1)&1]

        // EP gather for this step (consumed after MFMA) + next-token prefetch
        float epc[4][4];
        #pragma unroll
        for (int tau = 0; tau < 4; ++tau)
            ld_ep4(EP + (size_t)tokc * HIDD + jw + tau * 16 + lk * 4, epc[tau]);
        const int tokn = (t < 511) ? x[(t + 1) * BATCH + b0 + n] : 0;

        // B-frags (h_t), 8 conflict-free-ish b128 reads
        i32x4 B[8];
        #pragma unroll
        for (int kf = 0; kf < 8; ++kf)
            B[kf] = *reinterpret_cast<const i32x4*>(hq + ro + rdA[kf]);

        i32x4 acc[4] = {{0,0,0,0},{0,0,0,0},{0,0,0,0},{0,0,0,0}};
        #pragma unroll
        for (int kf = 0; kf < 8; ++kf) {
            acc[0] = __builtin_amdgcn_mfma_i32_16x16x64_i8(af[0][kf], B[kf], acc[0], 0, 0, 0);
            acc[1] = __builtin_amdgcn_mfma_i32_16x16x64_i8(af[1][kf], B[kf], acc[1], 0, 0, 0);
            acc[2] = __builtin_amdgcn_mfma_i32_16x16x64_i8(af[2][kf], B[kf], acc[2], 0, 0, 0);
            acc[3] = __builtin_amdgcn_mfma_i32_16x16x64_i8(af[3][kf], B[kf], acc[3], 0, 0, 0);
        }

        // dequant + EP + tanh + quantize + publish h_{t+1}
        #pragma unroll
        for (int tau = 0; tau < 4; ++tau) {
            unsigned pk = 0;
            #pragma unroll
            for (int r = 0; r < 4; ++r) {
                const float pre = fmaf((float)acc[tau][r], fs, epc[tau][r]);
                const int q = (int)rintf(tanh_fast(pre) * 127.f);
                pk |= ((unsigned)(q & 255)) << (8 * r);
            }
            *reinterpret_cast<unsigned*>(hq + wo + wrA[tau]) = pk;
        }
        tokc = tokn;
        __syncthreads();   // h_{t+1} visible; buf[t&1] free for next overwrite
    }

    // ---- FC epilogue: h_512 is in buffer 0 ----
    if (tid < 256) {
        const int n2 = tid >> 4, c = tid & 15;
        float dot = 0.f;
        for (int g = 0; g < 32; ++g) {
            const char* p = hq + n2 * 512 + ((g ^ n2) << 4);
            const float* wf = W_fc + c * HIDD + g * 16;
            #pragma unroll
            for (int i = 0; i < 16; ++i)
                dot += (float)((signed char)p[i]) * wf[i];
        }
        out[(b0 + n2) * NCLS + c] = dot * (1.f / 127.f) + b_fc[c];
    }
}

// ---------------------------------------------------------------------------
// Tier-C fallback (round-1, known good) for small ws.
__global__ void cvt_kernel(const float* __restrict__ W_ih,
                           const float* __restrict__ W_hh,
                           const float* __restrict__ b_ih,
                           const float* __restrict__ b_hh,
                           unsigned short* __restrict__ Wpk,
                           unsigned short* __restrict__ Wipk,
                           float* __restrict__ bias) {
    const int NW = HIDD * HIDD;
    const int NI = HIDD * EMBD;
    int gid = blockIdx.x * blockDim.x + threadIdx.x;
    if (gid < NW) {
        int j = gid >> 9, k = gid & (HIDD - 1);
        Wpk[((k >> 2) * HIDD + j) * 4 + (k & 3)] = f2bf(W_hh[gid]);
    } else if (gid < NW + NI) {
        int g2 = gid - NW, j = g2 >> 8, e = g2 & (EMBD - 1);
        Wipk[((e >> 2) * HIDD + j) * 4 + (e & 3)] = f2bf(W_ih[g2]);
    } else if (gid < NW + NI + HIDD) {
        int j = gid - NW - NI;
        bias[j] = b_ih[j] + b_hh[j];
    }
}

__global__ __launch_bounds__(512) void rnn_kernel(
    const int* __restrict__ x, const float* __restrict__ emb,
    const unsigned short* __restrict__ Wpk, const unsigned short* __restrict__ Wipk,
    const float* __restrict__ bias, const float* __restrict__ W_fc,
    const float* __restrict__ b_fc, float* __restrict__ out) {
    __shared__ __align__(16) float hL[HIDD];
    __shared__ __align__(16) float xe[EMBD];
    __shared__ float red[512];
    const int tid = threadIdx.x, b = blockIdx.x, j = tid;
    hL[j] = 0.0f;
    const float bj = bias[j];
    const ushort4* Wp4 = reinterpret_cast<const ushort4*>(Wpk);
    const ushort4* Wi4 = reinterpret_cast<const ushort4*>(Wipk);
    for (int t = 0; t < SEQ; ++t) {
        const int tok = x[t * BATCH + b];
        if (tid < EMBD) xe[tid] = emb[tok * EMBD + tid];
        __syncthreads();
        float a0 = bj, a1 = 0.0f;
        #pragma unroll 8
        for (int e4 = 0; e4 < EMBD / 4; ++e4) {
            const float4 xv = *reinterpret_cast<const float4*>(&xe[e4 * 4]);
            const ushort4 ww = Wi4[e4 * HIDD + j];
            a0 += xv.x * bfu(ww.x) + xv.y * bfu(ww.y);
            a1 += xv.z * bfu(ww.z) + xv.w * bfu(ww.w);
        }
        #pragma unroll 8
        for (int k4 = 0; k4 < HIDD / 4; ++k4) {
            const float4 hvv = *reinterpret_cast<const float4*>(&hL[k4 * 4]);
            const ushort4 ww = Wp4[k4 * HIDD + j];
            a0 += hvv.x * bfu(ww.x) + hvv.y * bfu(ww.y);
            a1 += hvv.z * bfu(ww.z) + hvv.w * bfu(ww.w);
        }
        __syncthreads();
        hL[j] = tanhf(a0 + a1);
    }
    __syncthreads();
    {
        const int c = tid >> 5, ks = tid & 31;
        float p = 0.0f;
        #pragma unroll
        for (int jj = 0; jj < HIDD / 32; ++jj) {
            const int jd = ks * (HIDD / 32) + jj;
            p += hL[jd] * W_fc[c * HIDD + jd];
        }
        red[tid] = p;
        __syncthreads();
        if (tid < NCLS) {
            float ss = b_fc[tid];
            #pragma unroll
            for (int i = 0; i < 32; ++i) ss += red[tid * 32 + i];
            out[b * NCLS + tid] = ss;
        }
    }
}

// ---------------------------------------------------------------------------
extern "C" void kernel_launch(void* const* d_in, const int* in_sizes, int n_in,
                              void* d_out, int out_size, void* d_ws, size_t ws_size,
                              hipStream_t stream) {
    const int*   x    = (const int*)  d_in[0];
    const float* emb  = (const float*)d_in[1];
    const float* W_ih = (const float*)d_in[2];
    const float* W_hh = (const float*)d_in[3];
    const float* b_ih = (const float*)d_in[4];
    const float* b_hh = (const float*)d_in[5];
    const float* W_fc = (const float*)d_in[6];
    const float* b_fc = (const float*)d_in[7];
    float* out = (float*)d_out;

    const size_t QW_B  = (size_t)HIDD * HIDD;       // 256 KB int8 W_hh
    const size_t SCL_B = 16;                        // scale slot
    const size_t WIH_B = (size_t)HIDD * EMBD * 2;   // 256 KB bf16 W_ih
    const size_t EPN   = (size_t)VOCAB * HIDD;
    const size_t HEAD  = QW_B + SCL_B + WIH_B;

    if (ws_size >= HEAD + EPN * 4) {
        signed char*    Wq    = (signed char*)d_ws;
        float*          scl   = (float*)((char*)d_ws + QW_B);
        unsigned short* Wih_b = (unsigned short*)((char*)d_ws + QW_B + SCL_B);
        float*          EP    = (float*)((char*)d_ws + HEAD);
        absmax_whh<<<1, 1024, 0, stream>>>(W_hh, scl);
        quant_whh<<<(HIDD * HIDD) / 256, 256, 0, stream>>>(W_hh, scl, Wq);
        cvt_wih<<<(HIDD * EMBD) / 256, 256, 0, stream>>>(W_ih, Wih_b);
        ep_gemm3<float><<<VOCAB / 64, 256, 0, stream>>>(emb, Wih_b, b_ih, b_hh, EP);
        rnn6<float><<<8, 512, 0, stream>>>(x, Wq, scl, EP, W_fc, b_fc, out);
    } else if (ws_size >= HEAD + EPN * 2) {
        signed char*    Wq    = (signed char*)d_ws;
        float*          scl   = (float*)((char*)d_ws + QW_B);
        unsigned short* Wih_b = (unsigned short*)((char*)d_ws + QW_B + SCL_B);
        unsigned short* EP    = (unsigned short*)((char*)d_ws + HEAD);
        absmax_whh<<<1, 1024, 0, stream>>>(W_hh, scl);
        quant_whh<<<(HIDD * HIDD) / 256, 256, 0, stream>>>(W_hh, scl, Wq);
        cvt_wih<<<(HIDD * EMBD) / 256, 256, 0, stream>>>(W_ih, Wih_b);
        ep_gemm3<unsigned short><<<VOCAB / 64, 256, 0, stream>>>(emb, Wih_b, b_ih, b_hh, EP);
        rnn6<unsigned short><<<8, 512, 0, stream>>>(x, Wq, scl, EP, W_fc, b_fc, out);
    } else {
        unsigned short* Wpk  = (unsigned short*)d_ws;
        unsigned short* Wipk = Wpk + HIDD * HIDD;
        float*          bias = (float*)(Wipk + HIDD * EMBD);
        const int total = HIDD * HIDD + HIDD * EMBD + HIDD;
        cvt_kernel<<<(total + 255) / 256, 256, 0, stream>>>(W_ih, W_hh, b_ih, b_hh, Wpk, Wipk, bias);
        rnn_kernel<<<BATCH, 512, 0, stream>>>(x, emb, Wpk, Wipk, bias, W_fc, b_fc, out);
    }
}

// Round 7
// 780.811 us; speedup vs baseline: 2.7768x; 1.6192x over previous
//
#include <hip/hip_runtime.h>
#include <hip/hip_bf16.h>

#define SEQ   512
#define BATCH 128
#define EMBD  256
#define HIDD  512
#define NCLS  16
#define VOCAB 32000

typedef unsigned long long u64;
typedef __attribute__((ext_vector_type(8))) short  short8;
typedef __attribute__((ext_vector_type(4))) float  f32x4;
typedef __attribute__((ext_vector_type(4))) int    i32x4;

__device__ __forceinline__ float bfu(unsigned short u) {
    return __uint_as_float(((unsigned int)u) << 16);
}
__device__ __forceinline__ unsigned short f2bf(float f) {
    __hip_bfloat16 h = __float2bfloat16(f);
    return *reinterpret_cast<unsigned short*>(&h);
}
__device__ __forceinline__ float rcp_fast(float x) {
    float r;
    asm("v_rcp_f32 %0, %1" : "=v"(r) : "v"(x));
    return r;
}
// q = rint(127 * tanh(x)) in ~10 VALU ops (no IEEE divide)
__device__ __forceinline__ int tanh_q127(float x) {
    const float xc = fminf(fmaxf(x, -12.f), 12.f);
    const float e  = __expf(xc + xc);          // e^{2x} (v_exp + mul)
    const float r  = rcp_fast(e + 1.f);
    return (int)rintf(fmaf(r, -254.f, 127.f)); // 127*(1 - 2r)
}
__device__ __forceinline__ float tanh_fast(float x) {
    const float xc = fminf(fmaxf(x, -12.f), 12.f);
    const float e  = __expf(xc + xc);
    return fmaf(rcp_fast(e + 1.f), -2.f, 1.f);
}
__device__ __forceinline__ void ep_store(float* p, float v)          { *p = v; }
__device__ __forceinline__ void ep_store(unsigned short* p, float v) { *p = f2bf(v); }

// ---------------------------------------------------------------------------
// scl layout (floats): [0]=absmax, [1]=sW*sh, [2]=absmax bits (u32, atomicMax)
__global__ void init_scl(float* __restrict__ scl) {
    if (threadIdx.x == 0) reinterpret_cast<unsigned*>(scl)[2] = 0u;
}

__global__ __launch_bounds__(256) void absmax_whh2(const float* __restrict__ W,
                                                   float* __restrict__ scl) {
    __shared__ float red[256];
    float m = 0.f;
    for (int i = blockIdx.x * 256 + threadIdx.x; i < (HIDD * HIDD) / 4; i += 64 * 256) {
        const float4 v = reinterpret_cast<const float4*>(W)[i];
        m = fmaxf(m, fmaxf(fmaxf(fabsf(v.x), fabsf(v.y)),
                           fmaxf(fabsf(v.z), fabsf(v.w))));
    }
    red[threadIdx.x] = m;
    __syncthreads();
    for (int s = 128; s > 0; s >>= 1) {
        if (threadIdx.x < s) red[threadIdx.x] = fmaxf(red[threadIdx.x], red[threadIdx.x + s]);
        __syncthreads();
    }
    if (threadIdx.x == 0)
        atomicMax(reinterpret_cast<unsigned*>(scl) + 2, __float_as_uint(red[0]));
}

// W_hh fp32 -> int8 row-major; thread 0 finalizes the scales.
__global__ void quant_whh2(const float* __restrict__ W, float* __restrict__ scl,
                           signed char* __restrict__ Wq) {
    const int i = blockIdx.x * 256 + threadIdx.x;
    const float am  = __uint_as_float(reinterpret_cast<unsigned*>(scl)[2]);
    const float inv = 127.f / am;
    Wq[i] = (signed char)(int)rintf(W[i] * inv);
    if (i == 0) { scl[0] = am; scl[1] = am / 16129.f; }   // (am/127)*(1/127)
}

// W_ih fp32 -> bf16 row-major.
__global__ void cvt_wih(const float* __restrict__ W, unsigned short* __restrict__ Wb) {
    const int i = blockIdx.x * 256 + threadIdx.x;
    Wb[i] = f2bf(W[i]);
}

// ---------------------------------------------------------------------------
// EP[v][j] = emb[v]·W_ih[j] + b_ih[j] + b_hh[j].  grid 500 x 256 thr.
template <typename EPT>
__global__ __launch_bounds__(256) void ep_gemm3(
    const float* __restrict__ emb, const unsigned short* __restrict__ Wih_b,
    const float* __restrict__ b_ih, const float* __restrict__ b_hh,
    EPT* __restrict__ EP) {
    const int w = threadIdx.x >> 6, l = threadIdx.x & 63;
    const int n = l & 15, lk = l >> 4;
    const int mtile = blockIdx.x * 4 + w;
    const int arow  = mtile * 16 + n;

    short8 areg[8];
    #pragma unroll
    for (int kk = 0; kk < 8; ++kk) {
        const int k0 = kk * 32 + lk * 8;
        const float4 a0 = *reinterpret_cast<const float4*>(emb + arow * EMBD + k0);
        const float4 a1 = *reinterpret_cast<const float4*>(emb + arow * EMBD + k0 + 4);
        short8 t;
        t[0]=(short)f2bf(a0.x); t[1]=(short)f2bf(a0.y); t[2]=(short)f2bf(a0.z); t[3]=(short)f2bf(a0.w);
        t[4]=(short)f2bf(a1.x); t[5]=(short)f2bf(a1.y); t[6]=(short)f2bf(a1.z); t[7]=(short)f2bf(a1.w);
        areg[kk] = t;
    }

    for (int nt = 0; nt < 32; ++nt) {
        const int col  = nt * 16 + n;
        const float bias = b_ih[col] + b_hh[col];
        f32x4 accA = {0.f,0.f,0.f,0.f}, accB = {0.f,0.f,0.f,0.f};
        #pragma unroll
        for (int kk = 0; kk < 8; ++kk) {
            const short8 bb = *reinterpret_cast<const short8*>(
                Wih_b + (size_t)col * EMBD + kk * 32 + lk * 8);
            if (kk & 1) accB = __builtin_amdgcn_mfma_f32_16x16x32_bf16(areg[kk], bb, accB, 0, 0, 0);
            else        accA = __builtin_amdgcn_mfma_f32_16x16x32_bf16(areg[kk], bb, accA, 0, 0, 0);
        }
        const f32x4 ac = accA + accB;
        #pragma unroll
        for (int r = 0; r < 4; ++r)
            ep_store(EP + (size_t)(mtile * 16 + lk * 4 + r) * HIDD + col, ac[r] + bias);
    }
}

// ---------------------------------------------------------------------------
// int8 weights-stationary RNN (r6 structure) + 1-step-ahead bf16 EP prefetch
// + cheap quantized tanh. grid = 8, 512 thr (8 waves, 2/SIMD).
// Wave w owns cols [w*64,w*64+64): all weights in 128 regs/thread (i8 A-frags).
// h int8 double-buffered in LDS (2 x 8 KB), 16B-granule XOR swizzle.
__global__ __launch_bounds__(512, 2) void rnn7(
    const int*            __restrict__ x,
    const signed char*    __restrict__ Wq,    // int8 [512][512]
    const float*          __restrict__ scl,   // [1] = sW*sh
    const unsigned short* __restrict__ EP,    // bf16 [VOCAB][512]
    const float*          __restrict__ W_fc,
    const float*          __restrict__ b_fc,
    float*                __restrict__ out) {

    __shared__ __align__(16) char hq[2 * 16 * 512];   // 16 KB total

    const int tid = threadIdx.x;
    const int w   = tid >> 6, l = tid & 63;
    const int n   = l & 15,  lk = l >> 4;
    const int b0  = blockIdx.x * 16;
    const int jw  = w * 64;
    const float fs = scl[1];

    // loop-invariant LDS byte offsets (into buffer 0)
    int rdA[8];
    #pragma unroll
    for (int kf = 0; kf < 8; ++kf) {
        const int g = kf * 4 + lk;
        rdA[kf] = n * 512 + ((g ^ n) << 4);
    }
    int wrA[4];
    #pragma unroll
    for (int tau = 0; tau < 4; ++tau) {
        const int j0 = jw + tau * 16 + lk * 4;
        wrA[tau] = n * 512 + (((j0 >> 4) ^ n) << 4) + (j0 & 15);
    }

    // per-lane EP base (this thread always reads the same 4 ushort4 slots of a row)
    const unsigned short* const epb = EP + jw + lk * 4;

    // ---- register-resident int8 A-frags: wave's 64 weight rows ----
    i32x4 af[4][8];
    #pragma unroll
    for (int tau = 0; tau < 4; ++tau)
        #pragma unroll
        for (int kf = 0; kf < 8; ++kf)
            af[tau][kf] = *reinterpret_cast<const i32x4*>(
                Wq + (size_t)(jw + tau * 16 + n) * HIDD + kf * 64 + lk * 16);

    // ---- t = 0: h1 = tanh(EP[tok0]) -> buffer 1 ----
    {
        const int tok0 = x[b0 + n];
        #pragma unroll
        for (int tau = 0; tau < 4; ++tau) {
            const ushort4 v = *reinterpret_cast<const ushort4*>(
                epb + (size_t)tok0 * HIDD + tau * 16);
            unsigned pk = 0;
            pk |= ((unsigned)(tanh_q127(bfu(v.x)) & 255));
            pk |= ((unsigned)(tanh_q127(bfu(v.y)) & 255)) << 8;
            pk |= ((unsigned)(tanh_q127(bfu(v.z)) & 255)) << 16;
            pk |= ((unsigned)(tanh_q127(bfu(v.w)) & 255)) << 24;
            *reinterpret_cast<unsigned*>(hq + 8192 + wrA[tau]) = pk;
        }
    }

    // ---- prefetch EP for t=1 (raw bf16 carry) + token for t=2 ----
    ushort4 pc[4];
    {
        const int tok1 = x[BATCH + b0 + n];
        #pragma unroll
        for (int tau = 0; tau < 4; ++tau)
            pc[tau] = *reinterpret_cast<const ushort4*>(
                epb + (size_t)tok1 * HIDD + tau * 16);
    }
    int tkn = x[2 * BATCH + b0 + n];   // token for step 2
    __syncthreads();

    #pragma unroll 2
    for (int t = 1; t <= 511; ++t) {
        const int ro = (t & 1) << 13;          // read buf[t&1]
        const int wo = 8192 - ro;              // write buf[(t+1)&1]

        // issue EP prefetch for step t+1 (token carried from last iter) and
        // the token gather for step t+2 — both consumed next iteration.
        ushort4 pn[4];
        #pragma unroll
        for (int tau = 0; tau < 4; ++tau)
            pn[tau] = *reinterpret_cast<const ushort4*>(
                epb + (size_t)tkn * HIDD + tau * 16);
        const int t2 = (t + 2 <= 511) ? (t + 2) : 511;
        const int tknn = x[t2 * BATCH + b0 + n];

        // B-frags (h_t), 8 swizzled b128 reads
        i32x4 B[8];
        #pragma unroll
        for (int kf = 0; kf < 8; ++kf)
            B[kf] = *reinterpret_cast<const i32x4*>(hq + ro + rdA[kf]);

        i32x4 acc[4] = {{0,0,0,0},{0,0,0,0},{0,0,0,0},{0,0,0,0}};
        #pragma unroll
        for (int kf = 0; kf < 8; ++kf) {
            acc[0] = __builtin_amdgcn_mfma_i32_16x16x64_i8(af[0][kf], B[kf], acc[0], 0, 0, 0);
            acc[1] = __builtin_amdgcn_mfma_i32_16x16x64_i8(af[1][kf], B[kf], acc[1], 0, 0, 0);
            acc[2] = __builtin_amdgcn_mfma_i32_16x16x64_i8(af[2][kf], B[kf], acc[2], 0, 0, 0);
            acc[3] = __builtin_amdgcn_mfma_i32_16x16x64_i8(af[3][kf], B[kf], acc[3], 0, 0, 0);
        }

        // dequant + EP (prefetched last iter) + tanh + quantize + publish
        #pragma unroll
        for (int tau = 0; tau < 4; ++tau) {
            const float e0 = bfu(pc[tau].x), e1 = bfu(pc[tau].y);
            const float e2 = bfu(pc[tau].z), e3 = bfu(pc[tau].w);
            unsigned pk = 0;
            pk |= ((unsigned)(tanh_q127(fmaf((float)acc[tau][0], fs, e0)) & 255));
            pk |= ((unsigned)(tanh_q127(fmaf((float)acc[tau][1], fs, e1)) & 255)) << 8;
            pk |= ((unsigned)(tanh_q127(fmaf((float)acc[tau][2], fs, e2)) & 255)) << 16;
            pk |= ((unsigned)(tanh_q127(fmaf((float)acc[tau][3], fs, e3)) & 255)) << 24;
            *reinterpret_cast<unsigned*>(hq + wo + wrA[tau]) = pk;
        }
        #pragma unroll
        for (int tau = 0; tau < 4; ++tau) pc[tau] = pn[tau];
        tkn = tknn;
        __syncthreads();   // h_{t+1} visible; buf[t&1] free next iteration
    }

    // ---- FC epilogue: h_512 is in buffer 0 ----
    if (tid < 256) {
        const int n2 = tid >> 4, c = tid & 15;
        float dot = 0.f;
        for (int g = 0; g < 32; ++g) {
            const char* p = hq + n2 * 512 + ((g ^ n2) << 4);
            const float* wf = W_fc + c * HIDD + g * 16;
            #pragma unroll
            for (int i = 0; i < 16; ++i)
                dot += (float)((signed char)p[i]) * wf[i];
        }
        out[(b0 + n2) * NCLS + c] = dot * (1.f / 127.f) + b_fc[c];
    }
}

// ---------------------------------------------------------------------------
// Tier-C fallback (round-1, known good) for small ws.
__global__ void cvt_kernel(const float* __restrict__ W_ih,
                           const float* __restrict__ W_hh,
                           const float* __restrict__ b_ih,
                           const float* __restrict__ b_hh,
                           unsigned short* __restrict__ Wpk,
                           unsigned short* __restrict__ Wipk,
                           float* __restrict__ bias) {
    const int NW = HIDD * HIDD;
    const int NI = HIDD * EMBD;
    int gid = blockIdx.x * blockDim.x + threadIdx.x;
    if (gid < NW) {
        int j = gid >> 9, k = gid & (HIDD - 1);
        Wpk[((k >> 2) * HIDD + j) * 4 + (k & 3)] = f2bf(W_hh[gid]);
    } else if (gid < NW + NI) {
        int g2 = gid - NW, j = g2 >> 8, e = g2 & (EMBD - 1);
        Wipk[((e >> 2) * HIDD + j) * 4 + (e & 3)] = f2bf(W_ih[g2]);
    } else if (gid < NW + NI + HIDD) {
        int j = gid - NW - NI;
        bias[j] = b_ih[j] + b_hh[j];
    }
}

__global__ __launch_bounds__(512) void rnn_kernel(
    const int* __restrict__ x, const float* __restrict__ emb,
    const unsigned short* __restrict__ Wpk, const unsigned short* __restrict__ Wipk,
    const float* __restrict__ bias, const float* __restrict__ W_fc,
    const float* __restrict__ b_fc, float* __restrict__ out) {
    __shared__ __align__(16) float hL[HIDD];
    __shared__ __align__(16) float xe[EMBD];
    __shared__ float red[512];
    const int tid = threadIdx.x, b = blockIdx.x, j = tid;
    hL[j] = 0.0f;
    const float bj = bias[j];
    const ushort4* Wp4 = reinterpret_cast<const ushort4*>(Wpk);
    const ushort4* Wi4 = reinterpret_cast<const ushort4*>(Wipk);
    for (int t = 0; t < SEQ; ++t) {
        const int tok = x[t * BATCH + b];
        if (tid < EMBD) xe[tid] = emb[tok * EMBD + tid];
        __syncthreads();
        float a0 = bj, a1 = 0.0f;
        #pragma unroll 8
        for (int e4 = 0; e4 < EMBD / 4; ++e4) {
            const float4 xv = *reinterpret_cast<const float4*>(&xe[e4 * 4]);
            const ushort4 ww = Wi4[e4 * HIDD + j];
            a0 += xv.x * bfu(ww.x) + xv.y * bfu(ww.y);
            a1 += xv.z * bfu(ww.z) + xv.w * bfu(ww.w);
        }
        #pragma unroll 8
        for (int k4 = 0; k4 < HIDD / 4; ++k4) {
            const float4 hvv = *reinterpret_cast<const float4*>(&hL[k4 * 4]);
            const ushort4 ww = Wp4[k4 * HIDD + j];
            a0 += hvv.x * bfu(ww.x) + hvv.y * bfu(ww.y);
            a1 += hvv.z * bfu(ww.z) + hvv.w * bfu(ww.w);
        }
        __syncthreads();
        hL[j] = tanhf(a0 + a1);
    }
    __syncthreads();
    {
        const int c = tid >> 5, ks = tid & 31;
        float p = 0.0f;
        #pragma unroll
        for (int jj = 0; jj < HIDD / 32; ++jj) {
            const int jd = ks * (HIDD / 32) + jj;
            p += hL[jd] * W_fc[c * HIDD + jd];
        }
        red[tid] = p;
        __syncthreads();
        if (tid < NCLS) {
            float ss = b_fc[tid];
            #pragma unroll
            for (int i = 0; i < 32; ++i) ss += red[tid * 32 + i];
            out[b * NCLS + tid] = ss;
        }
    }
}

// ---------------------------------------------------------------------------
extern "C" void kernel_launch(void* const* d_in, const int* in_sizes, int n_in,
                              void* d_out, int out_size, void* d_ws, size_t ws_size,
                              hipStream_t stream) {
    const int*   x    = (const int*)  d_in[0];
    const float* emb  = (const float*)d_in[1];
    const float* W_ih = (const float*)d_in[2];
    const float* W_hh = (const float*)d_in[3];
    const float* b_ih = (const float*)d_in[4];
    const float* b_hh = (const float*)d_in[5];
    const float* W_fc = (const float*)d_in[6];
    const float* b_fc = (const float*)d_in[7];
    float* out = (float*)d_out;

    const size_t QW_B  = (size_t)HIDD * HIDD;       // 256 KB int8 W_hh
    const size_t SCL_B = 16;                        // scale slots
    const size_t WIH_B = (size_t)HIDD * EMBD * 2;   // 256 KB bf16 W_ih
    const size_t EPN   = (size_t)VOCAB * HIDD;
    const size_t HEAD  = QW_B + SCL_B + WIH_B;

    if (ws_size >= HEAD + EPN * 2) {
        signed char*    Wq    = (signed char*)d_ws;
        float*          scl   = (float*)((char*)d_ws + QW_B);
        unsigned short* Wih_b = (unsigned short*)((char*)d_ws + QW_B + SCL_B);
        unsigned short* EP    = (unsigned short*)((char*)d_ws + HEAD);
        init_scl<<<1, 64, 0, stream>>>(scl);
        absmax_whh2<<<64, 256, 0, stream>>>(W_hh, scl);
        quant_whh2<<<(HIDD * HIDD) / 256, 256, 0, stream>>>(W_hh, scl, Wq);
        cvt_wih<<<(HIDD * EMBD) / 256, 256, 0, stream>>>(W_ih, Wih_b);
        ep_gemm3<unsigned short><<<VOCAB / 64, 256, 0, stream>>>(emb, Wih_b, b_ih, b_hh, EP);
        rnn7<<<8, 512, 0, stream>>>(x, Wq, scl, EP, W_fc, b_fc, out);
    } else {
        unsigned short* Wpk  = (unsigned short*)d_ws;
        unsigned short* Wipk = Wpk + HIDD * HIDD;
        float*          bias = (float*)(Wipk + HIDD * EMBD);
        const int total = HIDD * HIDD + HIDD * EMBD + HIDD;
        cvt_kernel<<<(total + 255) / 256, 256, 0, stream>>>(W_ih, W_hh, b_ih, b_hh, Wpk, Wipk, bias);
        rnn_kernel<<<BATCH, 512, 0, stream>>>(x, emb, Wpk, Wipk, bias, W_fc, b_fc, out);
    }
}